// Round 1
// baseline (213.423 us; speedup 1.0000x reference)
//
#include <hip/hip_runtime.h>
#include <cstdint>

#define NTOPK 13
#define FEPS 1e-9f

// ---------------------------------------------------------------------------
// Kernel A: per (b,l) argmax over g of IoU(gt[b,g], pred[b,l]).
// jnp.argmax semantics: first occurrence of max (strict > update, ascending g).
// ---------------------------------------------------------------------------
__global__ void k_iou_argmax(const float4* __restrict__ pred_bboxes,
                             const float4* __restrict__ gt_bboxes,
                             int* __restrict__ iou_argmax,
                             int B, int L, int n) {
    extern __shared__ float4 sgt[];  // n boxes
    int b = blockIdx.y;
    for (int g = threadIdx.x; g < n; g += blockDim.x)
        sgt[g] = gt_bboxes[(size_t)b * n + g];
    __syncthreads();
    int l = blockIdx.x * blockDim.x + threadIdx.x;
    if (l >= L) return;
    float4 p = pred_bboxes[(size_t)b * L + l];
    float ap = (p.z - p.x) * (p.w - p.y);
    float best = -1.0f;
    int bi = 0;
    for (int g = 0; g < n; ++g) {
        float4 gb = sgt[g];
        float iw = fmaxf(fminf(gb.z, p.z) - fmaxf(gb.x, p.x), 0.0f);
        float ih = fmaxf(fminf(gb.w, p.w) - fmaxf(gb.y, p.y), 0.0f);
        float inter = iw * ih;
        float ag = (gb.z - gb.x) * (gb.w - gb.y);
        float iou = inter / (((ag + ap) - inter) + 1e-9f);
        if (iou > best) { best = iou; bi = g; }
    }
    iou_argmax[(size_t)b * L + l] = bi;
}

// ---------------------------------------------------------------------------
// Kernel B: one block per (b,g). Compute metric[l] = in_gts * score * iou^6
// into LDS, then 13 rounds of block-argmax with lax.top_k tie semantics
// (value desc, index asc). Picked anchors that are in-gts set bit g in the
// per-(b,l) mask (atomicOr).
// ---------------------------------------------------------------------------
__global__ __launch_bounds__(256) void k_topk(
        const float* __restrict__ pred_scores,
        const float4* __restrict__ pred_bboxes,
        const float2* __restrict__ anchor_points,
        const int* __restrict__ gt_labels,
        const float4* __restrict__ gt_bboxes,
        const float* __restrict__ pad_gt_mask,
        uint32_t* __restrict__ maskbits,
        int B, int L, int C, int n, int W) {
    int bg = blockIdx.x;
    if (pad_gt_mask[bg] == 0.0f) return;  // masked gt -> contributes nothing
    int b = bg / n;
    int g = bg - b * n;

    extern __shared__ float smet[];  // L floats
    __shared__ float rv[256];
    __shared__ int   ri[256];
    __shared__ int   s_topk[NTOPK];

    float4 gb = gt_bboxes[bg];
    int label = gt_labels[bg];
    float ag = (gb.z - gb.x) * (gb.w - gb.y);
    const float4* pb = pred_bboxes + (size_t)b * L;
    const float*  ps = pred_scores + ((size_t)b * L) * C + label;
    int t = threadIdx.x;

    for (int l = t; l < L; l += 256) {
        float2 a = anchor_points[l];
        float dmin = fminf(fminf(a.x - gb.x, a.y - gb.y),
                           fminf(gb.z - a.x, gb.w - a.y));
        float m = 0.0f;
        if (dmin > FEPS) {
            float4 p = pb[l];
            float iw = fmaxf(fminf(gb.z, p.z) - fmaxf(gb.x, p.x), 0.0f);
            float ih = fmaxf(fminf(gb.w, p.w) - fmaxf(gb.y, p.y), 0.0f);
            float inter = iw * ih;
            float ap = (p.z - p.x) * (p.w - p.y);
            float iou = inter / (((ag + ap) - inter) + 1e-9f);
            m = ps[(size_t)l * C] * powf(iou, 6.0f);
        }
        smet[l] = m;
    }
    __syncthreads();

    for (int k = 0; k < NTOPK; ++k) {
        float bv = -1.0f;
        int bi = 0x7fffffff;
        for (int l = t; l < L; l += 256) {
            float v = smet[l];
            if (v > bv) { bv = v; bi = l; }  // ascending scan: keeps lowest idx on ties
        }
        rv[t] = bv; ri[t] = bi;
        __syncthreads();
        for (int s = 128; s > 0; s >>= 1) {
            if (t < s) {
                float ov = rv[t + s]; int oi = ri[t + s];
                if (ov > rv[t] || (ov == rv[t] && oi < ri[t])) { rv[t] = ov; ri[t] = oi; }
            }
            __syncthreads();
        }
        if (t == 0) {
            int w = ri[0];
            s_topk[k] = w;
            smet[w] = -1.0f;  // mark taken
        }
        __syncthreads();
    }

    if (t < NTOPK) {
        int l = s_topk[t];
        float2 a = anchor_points[l];
        float dmin = fminf(fminf(a.x - gb.x, a.y - gb.y),
                           fminf(gb.z - a.x, gb.w - a.y));
        if (dmin > FEPS) {
            atomicOr(&maskbits[(size_t)((size_t)b * L + l) * W + (g >> 5)],
                     1u << (g & 31));
        }
    }
}

// ---------------------------------------------------------------------------
// Kernel C: per (b,l): resolve assignment, write labels + bboxes, and
// atomically accumulate per-gt max(align), max(iou) over assigned anchors.
// ---------------------------------------------------------------------------
__global__ void k_assign(const float* __restrict__ pred_scores,
                         const float4* __restrict__ pred_bboxes,
                         const float4* __restrict__ gt_bboxes,
                         const int* __restrict__ gt_labels,
                         const uint32_t* __restrict__ maskbits,
                         const int* __restrict__ iou_argmax,
                         const int* __restrict__ bg_ptr,
                         int* __restrict__ assigned_g,
                         float* __restrict__ align_val,
                         uint32_t* __restrict__ max_m,
                         uint32_t* __restrict__ max_i,
                         float* __restrict__ out_labels,
                         float4* __restrict__ out_bboxes,
                         int B, int L, int C, int n, int W) {
    int idx = blockIdx.x * blockDim.x + threadIdx.x;
    if (idx >= B * L) return;
    int b = idx / L;

    int sum = 0, firstg = -1;
    for (int w = 0; w < W; ++w) {
        uint32_t bits = maskbits[(size_t)idx * W + w];
        if (bits && firstg < 0) firstg = w * 32 + __ffs(bits) - 1;
        sum += __popc(bits);
    }
    int g;
    if (sum == 0) g = -1;
    else if (sum == 1) g = firstg;
    else g = iou_argmax[idx];  // is_max_iou replacement
    assigned_g[idx] = g;

    float av = 0.0f;
    if (g >= 0) {
        float4 gb = gt_bboxes[(size_t)b * n + g];
        float4 p = pred_bboxes[idx];
        float iw = fmaxf(fminf(gb.z, p.z) - fmaxf(gb.x, p.x), 0.0f);
        float ih = fmaxf(fminf(gb.w, p.w) - fmaxf(gb.y, p.y), 0.0f);
        float inter = iw * ih;
        float ag = (gb.z - gb.x) * (gb.w - gb.y);
        float ap = (p.z - p.x) * (p.w - p.y);
        float iou = inter / (((ag + ap) - inter) + 1e-9f);
        int label = gt_labels[(size_t)b * n + g];
        float score = pred_scores[(size_t)idx * C + label];
        av = score * powf(iou, 6.0f);
        atomicMax(&max_m[(size_t)b * n + g], __float_as_uint(av));
        atomicMax(&max_i[(size_t)b * n + g], __float_as_uint(iou));
        out_labels[idx] = (float)label;
        out_bboxes[idx] = gb;
    } else {
        out_labels[idx] = (float)(*bg_ptr);
        out_bboxes[idx] = gt_bboxes[(size_t)b * n];  // agi==0 gather, unmasked
    }
    align_val[idx] = av;
}

// ---------------------------------------------------------------------------
// Kernel D: elementwise over B*L*C: one-hot * rescaled align. Coalesced.
// ---------------------------------------------------------------------------
__global__ void k_scores(const int* __restrict__ assigned_g,
                         const float* __restrict__ align_val,
                         const uint32_t* __restrict__ max_m,
                         const uint32_t* __restrict__ max_i,
                         const int* __restrict__ gt_labels,
                         const int* __restrict__ bg_ptr,
                         float* __restrict__ out_scores,
                         int B, int L, int C, int n, int total) {
    int idx = blockIdx.x * blockDim.x + threadIdx.x;
    if (idx >= total) return;
    int c = idx % C;
    int bl = idx / C;
    int g = assigned_g[bl];
    float v = 0.0f;
    if (g >= 0) {
        int b = bl / L;
        int label = gt_labels[(size_t)b * n + g];
        int bg = *bg_ptr;
        int cls = (c < bg) ? c : c + 1;  // keep[] mapping (skip bg column)
        if (cls == label) {
            float mm = __uint_as_float(max_m[(size_t)b * n + g]);
            float mi = __uint_as_float(max_i[(size_t)b * n + g]);
            v = align_val[bl] / (mm + FEPS) * mi;
        }
    }
    out_scores[idx] = v;
}

// ---------------------------------------------------------------------------
extern "C" void kernel_launch(void* const* d_in, const int* in_sizes, int n_in,
                              void* d_out, int out_size, void* d_ws, size_t ws_size,
                              hipStream_t stream) {
    const float*  pred_scores   = (const float*)d_in[0];
    const float4* pred_bboxes   = (const float4*)d_in[1];
    const float2* anchor_points = (const float2*)d_in[2];
    const int*    gt_labels     = (const int*)d_in[3];
    const float4* gt_bboxes     = (const float4*)d_in[4];
    const float*  pad_gt_mask   = (const float*)d_in[5];
    const int*    bg_ptr        = (const int*)d_in[6];

    const int L = in_sizes[2] / 2;
    const int B = in_sizes[1] / (L * 4);
    const int C = in_sizes[0] / (B * L);
    const int n = in_sizes[3] / B;
    const int W = (n + 31) / 32;

    char* ws = (char*)d_ws;
    int*      iou_arg    = (int*)ws;       ws += (size_t)B * L * sizeof(int);
    int*      assigned_g = (int*)ws;       ws += (size_t)B * L * sizeof(int);
    float*    align_val  = (float*)ws;     ws += (size_t)B * L * sizeof(float);
    uint32_t* maskbits   = (uint32_t*)ws;  ws += (size_t)B * L * W * sizeof(uint32_t);
    uint32_t* max_m      = (uint32_t*)ws;  ws += (size_t)B * n * sizeof(uint32_t);
    uint32_t* max_i      = (uint32_t*)ws;  ws += (size_t)B * n * sizeof(uint32_t);

    float*  out_labels = (float*)d_out;
    float4* out_bboxes = (float4*)((float*)d_out + (size_t)B * L);
    float*  out_scores = (float*)d_out + (size_t)B * L * 5;

    hipMemsetAsync(maskbits, 0, (size_t)B * L * W * sizeof(uint32_t), stream);
    hipMemsetAsync(max_m, 0, (size_t)B * n * sizeof(uint32_t), stream);
    hipMemsetAsync(max_i, 0, (size_t)B * n * sizeof(uint32_t), stream);

    {
        dim3 grid((L + 255) / 256, B);
        k_iou_argmax<<<grid, 256, n * sizeof(float4), stream>>>(
            pred_bboxes, gt_bboxes, iou_arg, B, L, n);
    }
    k_topk<<<B * n, 256, (size_t)L * sizeof(float), stream>>>(
        pred_scores, pred_bboxes, anchor_points, gt_labels, gt_bboxes,
        pad_gt_mask, maskbits, B, L, C, n, W);
    k_assign<<<(B * L + 255) / 256, 256, 0, stream>>>(
        pred_scores, pred_bboxes, gt_bboxes, gt_labels, maskbits, iou_arg,
        bg_ptr, assigned_g, align_val, max_m, max_i, out_labels, out_bboxes,
        B, L, C, n, W);
    {
        int total = B * L * C;
        k_scores<<<(total + 255) / 256, 256, 0, stream>>>(
            assigned_g, align_val, max_m, max_i, gt_labels, bg_ptr,
            out_scores, B, L, C, n, total);
    }
}

// Round 2
// 129.651 us; speedup vs baseline: 1.6461x; 1.6461x over previous
//
#include <hip/hip_runtime.h>
#include <cstdint>

#define NTOPK 13
#define FEPS 1e-9f
#define LMAX 8448            // max anchors supported by static LDS (L=8400)
#define NW2MAX 264           // ceil(LMAX/256)*8 bitmask words
#define CAP 2048             // compacted-positives capacity

// ---------------------------------------------------------------------------
// Kernel A: per (b,l) argmax over g of IoU(gt[b,g], pred[b,l]).
// jnp.argmax semantics: first occurrence of max (strict > update, ascending g).
// ---------------------------------------------------------------------------
__global__ void k_iou_argmax(const float4* __restrict__ pred_bboxes,
                             const float4* __restrict__ gt_bboxes,
                             int* __restrict__ iou_argmax,
                             int B, int L, int n) {
    extern __shared__ float4 sgt[];  // n boxes
    int b = blockIdx.y;
    for (int g = threadIdx.x; g < n; g += blockDim.x)
        sgt[g] = gt_bboxes[(size_t)b * n + g];
    __syncthreads();
    int l = blockIdx.x * blockDim.x + threadIdx.x;
    if (l >= L) return;
    float4 p = pred_bboxes[(size_t)b * L + l];
    float ap = (p.z - p.x) * (p.w - p.y);
    float best = -1.0f;
    int bi = 0;
    for (int g = 0; g < n; ++g) {
        float4 gb = sgt[g];
        float iw = fmaxf(fminf(gb.z, p.z) - fmaxf(gb.x, p.x), 0.0f);
        float ih = fmaxf(fminf(gb.w, p.w) - fmaxf(gb.y, p.y), 0.0f);
        float inter = iw * ih;
        float ag = (gb.z - gb.x) * (gb.w - gb.y);
        float iou = inter / (((ag + ap) - inter) + 1e-9f);
        if (iou > best) { best = iou; bi = g; }
    }
    iou_argmax[(size_t)b * L + l] = bi;
}

// ---------------------------------------------------------------------------
// metric[l] for one gt. Identical arithmetic to the reference.
// ---------------------------------------------------------------------------
__device__ __forceinline__ float tal_metric(int l, float4 gb, float ag,
                                            const float4* __restrict__ pb,
                                            const float* __restrict__ ps,
                                            const float2* __restrict__ apt,
                                            int C) {
    float2 a = apt[l];
    float dmin = fminf(fminf(a.x - gb.x, a.y - gb.y),
                       fminf(gb.z - a.x, gb.w - a.y));
    float m = 0.0f;
    if (dmin > FEPS) {
        float4 p = pb[l];
        float iw = fmaxf(fminf(gb.z, p.z) - fmaxf(gb.x, p.x), 0.0f);
        float ih = fmaxf(fminf(gb.w, p.w) - fmaxf(gb.y, p.y), 0.0f);
        float inter = iw * ih;
        float ap2 = (p.z - p.x) * (p.w - p.y);
        float iou = inter / (((ag + ap2) - inter) + 1e-9f);
        m = ps[(size_t)l * C] * powf(iou, 6.0f);
    }
    return m;
}

// ---------------------------------------------------------------------------
// Kernel B: one block per (b,g). Sparse top-13:
//  - one metric pass; wave-ballot compaction of positives into LDS keys
//    (key = vbits<<32 | ~l, so key-desc == value desc then index asc),
//    plus a "nonzero" bitmask over anchors for the zero-fill.
//  - select top min(p,13) positives (wave shfl path for p<=64, block rounds
//    for p<=CAP, full recompute fallback beyond).
//  - pad with lowest-index zero-metric anchors (lax.top_k tie semantics).
//  - picks set bit g in the per-(b,l) mask iff anchor in gts.
// ---------------------------------------------------------------------------
__global__ __launch_bounds__(256) void k_topk(
        const float* __restrict__ pred_scores,
        const float4* __restrict__ pred_bboxes,
        const float2* __restrict__ anchor_points,
        const int* __restrict__ gt_labels,
        const float4* __restrict__ gt_bboxes,
        const float* __restrict__ pad_gt_mask,
        uint32_t* __restrict__ maskbits,
        int B, int L, int C, int n, int W) {
    int bg = blockIdx.x;
    if (pad_gt_mask[bg] == 0.0f) return;  // masked gt contributes nothing
    int b = bg / n;

    __shared__ uint64_t s_keys[CAP];
    __shared__ uint64_t s_red[256];
    __shared__ int      s_redi[256];
    __shared__ uint32_t s_nz[NW2MAX];
    __shared__ int      s_topk[NTOPK];
    __shared__ int      s_cnt;

    float4 gb = gt_bboxes[bg];
    int label = gt_labels[bg];
    float ag = (gb.z - gb.x) * (gb.w - gb.y);
    const float4* pb = pred_bboxes + (size_t)b * L;
    const float*  ps = pred_scores + ((size_t)b * L) * C + label;
    int t = threadIdx.x;
    int lane = t & 63;
    int NW2 = ((L + 255) / 256) * 8;

    if (t == 0) s_cnt = 0;
    for (int w = t; w < NW2; w += 256) s_nz[w] = 0;
    __syncthreads();

    // ---- phase 1: metric pass, compaction + nonzero bitmask ----
    for (int base = 0; base < L; base += 256) {
        int l = base + t;
        float m = 0.0f;
        bool inb = (l < L);
        if (inb) m = tal_metric(l, gb, ag, pb, ps, anchor_points, C);
        bool pos = inb && (m > 0.0f);
        bool nzb = pos || !inb;  // out-of-range anchors are never zero-fill picks
        uint64_t nzball = __ballot(nzb);
        int l0 = base + (t & ~63);  // first anchor covered by this wave
        if (lane == 0)  s_nz[l0 >> 5]       = (uint32_t)nzball;
        if (lane == 32) s_nz[(l0 >> 5) + 1] = (uint32_t)(nzball >> 32);
        uint64_t pball = __ballot(pos);
        int npos = __popcll(pball);
        int wbase = 0;
        if (lane == 0 && npos) wbase = atomicAdd(&s_cnt, npos);
        wbase = __shfl(wbase, 0);
        if (pos) {
            int off = wbase + __popcll(pball & ((1ull << lane) - 1));
            if (off < CAP)
                s_keys[off] = ((uint64_t)__float_as_uint(m) << 32) | (uint32_t)(~l);
        }
    }
    __syncthreads();
    int p = s_cnt;

    // ---- phase 2: select top min(p,13) positives ----
    if (p <= NTOPK) {
        if (t < p) s_topk[t] = (int)~(uint32_t)s_keys[t];
    } else if (p <= 64) {
        if (t < 64) {  // single full wave, barrier-free rounds
            uint64_t mykey = (t < p) ? s_keys[t] : 0ull;
            for (int k = 0; k < NTOPK; ++k) {
                uint64_t mk = mykey;
                for (int s = 1; s < 64; s <<= 1) {
                    uint64_t o = (uint64_t)__shfl_xor((unsigned long long)mk, s);
                    if (o > mk) mk = o;
                }
                if (t == 0) s_topk[k] = (int)~(uint32_t)mk;
                if (mykey == mk) mykey = 0ull;  // unique owner removes
            }
        }
    } else if (p <= CAP) {
        for (int k = 0; k < NTOPK; ++k) {
            uint64_t bk = 0; int bi = -1;
            for (int j = t; j < p; j += 256) {
                uint64_t key = s_keys[j];
                if (key > bk) { bk = key; bi = j; }
            }
            s_red[t] = bk; s_redi[t] = bi;
            __syncthreads();
            for (int s = 128; s > 0; s >>= 1) {
                if (t < s && s_red[t + s] > s_red[t]) {
                    s_red[t] = s_red[t + s]; s_redi[t] = s_redi[t + s];
                }
                __syncthreads();
            }
            if (t == 0) { s_topk[k] = (int)~(uint32_t)s_red[0]; s_keys[s_redi[0]] = 0ull; }
            __syncthreads();
        }
    } else {
        // correctness fallback (never taken for this data): recompute rounds
        for (int k = 0; k < NTOPK; ++k) {
            uint64_t bk = 0;
            for (int l = t; l < L; l += 256) {
                bool taken = false;
                for (int j = 0; j < k; ++j) taken |= (s_topk[j] == l);
                if (taken) continue;
                float m = tal_metric(l, gb, ag, pb, ps, anchor_points, C);
                uint64_t key = ((uint64_t)__float_as_uint(m) << 32) | (uint32_t)(~l);
                if (key > bk) bk = key;
            }
            s_red[t] = bk;
            __syncthreads();
            for (int s = 128; s > 0; s >>= 1) {
                if (t < s && s_red[t + s] > s_red[t]) s_red[t] = s_red[t + s];
                __syncthreads();
            }
            if (t == 0) s_topk[k] = (int)~(uint32_t)s_red[0];
            __syncthreads();
        }
        p = NTOPK;  // all 13 slots filled; skip zero-fill
    }
    __syncthreads();

    // ---- phase 3: zero-fill lowest-index zero-metric anchors ----
    if (t == 0 && p < NTOPK) {
        int need = NTOPK - p;
        int idx = p;
        for (int w = 0; w < NW2 && need > 0; ++w) {
            uint32_t bits = ~s_nz[w];
            while (bits && need > 0) {
                int j = __ffs(bits) - 1;
                bits &= bits - 1;
                s_topk[idx++] = w * 32 + j;
                --need;
            }
        }
    }
    __syncthreads();

    // ---- phase 4: set gt bit for picks that are in-gts ----
    if (t < NTOPK) {
        int l = s_topk[t];
        float2 a = anchor_points[l];
        float dmin = fminf(fminf(a.x - gb.x, a.y - gb.y),
                           fminf(gb.z - a.x, gb.w - a.y));
        if (dmin > FEPS) {
            int g = bg - b * n;
            atomicOr(&maskbits[(size_t)((size_t)b * L + l) * W + (g >> 5)],
                     1u << (g & 31));
        }
    }
}

// ---------------------------------------------------------------------------
// Kernel C: per (b,l): resolve assignment, write labels + bboxes, and
// atomically accumulate per-gt max(align), max(iou) over assigned anchors.
// ---------------------------------------------------------------------------
__global__ void k_assign(const float* __restrict__ pred_scores,
                         const float4* __restrict__ pred_bboxes,
                         const float4* __restrict__ gt_bboxes,
                         const int* __restrict__ gt_labels,
                         const uint32_t* __restrict__ maskbits,
                         const int* __restrict__ iou_argmax,
                         const int* __restrict__ bg_ptr,
                         int* __restrict__ assigned_g,
                         float* __restrict__ align_val,
                         uint32_t* __restrict__ max_m,
                         uint32_t* __restrict__ max_i,
                         float* __restrict__ out_labels,
                         float4* __restrict__ out_bboxes,
                         int B, int L, int C, int n, int W) {
    int idx = blockIdx.x * blockDim.x + threadIdx.x;
    if (idx >= B * L) return;
    int b = idx / L;

    int sum = 0, firstg = -1;
    for (int w = 0; w < W; ++w) {
        uint32_t bits = maskbits[(size_t)idx * W + w];
        if (bits && firstg < 0) firstg = w * 32 + __ffs(bits) - 1;
        sum += __popc(bits);
    }
    int g;
    if (sum == 0) g = -1;
    else if (sum == 1) g = firstg;
    else g = iou_argmax[idx];  // is_max_iou replacement
    assigned_g[idx] = g;

    float av = 0.0f;
    if (g >= 0) {
        float4 gb = gt_bboxes[(size_t)b * n + g];
        float4 p = pred_bboxes[idx];
        float iw = fmaxf(fminf(gb.z, p.z) - fmaxf(gb.x, p.x), 0.0f);
        float ih = fmaxf(fminf(gb.w, p.w) - fmaxf(gb.y, p.y), 0.0f);
        float inter = iw * ih;
        float ag = (gb.z - gb.x) * (gb.w - gb.y);
        float ap = (p.z - p.x) * (p.w - p.y);
        float iou = inter / (((ag + ap) - inter) + 1e-9f);
        int label = gt_labels[(size_t)b * n + g];
        float score = pred_scores[(size_t)idx * C + label];
        av = score * powf(iou, 6.0f);
        atomicMax(&max_m[(size_t)b * n + g], __float_as_uint(av));
        atomicMax(&max_i[(size_t)b * n + g], __float_as_uint(iou));
        out_labels[idx] = (float)label;
        out_bboxes[idx] = gb;
    } else {
        out_labels[idx] = (float)(*bg_ptr);
        out_bboxes[idx] = gt_bboxes[(size_t)b * n];  // agi==0 gather, unmasked
    }
    align_val[idx] = av;
}

// ---------------------------------------------------------------------------
// Kernel D: elementwise over B*L*C: one-hot * rescaled align. Coalesced.
// ---------------------------------------------------------------------------
__global__ void k_scores(const int* __restrict__ assigned_g,
                         const float* __restrict__ align_val,
                         const uint32_t* __restrict__ max_m,
                         const uint32_t* __restrict__ max_i,
                         const int* __restrict__ gt_labels,
                         const int* __restrict__ bg_ptr,
                         float* __restrict__ out_scores,
                         int B, int L, int C, int n, int total) {
    int idx = blockIdx.x * blockDim.x + threadIdx.x;
    if (idx >= total) return;
    int c = idx % C;
    int bl = idx / C;
    int g = assigned_g[bl];
    float v = 0.0f;
    if (g >= 0) {
        int b = bl / L;
        int label = gt_labels[(size_t)b * n + g];
        int bg = *bg_ptr;
        int cls = (c < bg) ? c : c + 1;  // keep[] mapping (skip bg column)
        if (cls == label) {
            float mm = __uint_as_float(max_m[(size_t)b * n + g]);
            float mi = __uint_as_float(max_i[(size_t)b * n + g]);
            v = align_val[bl] / (mm + FEPS) * mi;
        }
    }
    out_scores[idx] = v;
}

// ---------------------------------------------------------------------------
extern "C" void kernel_launch(void* const* d_in, const int* in_sizes, int n_in,
                              void* d_out, int out_size, void* d_ws, size_t ws_size,
                              hipStream_t stream) {
    const float*  pred_scores   = (const float*)d_in[0];
    const float4* pred_bboxes   = (const float4*)d_in[1];
    const float2* anchor_points = (const float2*)d_in[2];
    const int*    gt_labels     = (const int*)d_in[3];
    const float4* gt_bboxes     = (const float4*)d_in[4];
    const float*  pad_gt_mask   = (const float*)d_in[5];
    const int*    bg_ptr        = (const int*)d_in[6];

    const int L = in_sizes[2] / 2;
    const int B = in_sizes[1] / (L * 4);
    const int C = in_sizes[0] / (B * L);
    const int n = in_sizes[3] / B;
    const int W = (n + 31) / 32;

    // zero-initialized buffers first (single contiguous memset)
    char* ws = (char*)d_ws;
    uint32_t* maskbits   = (uint32_t*)ws;  ws += (size_t)B * L * W * sizeof(uint32_t);
    uint32_t* max_m      = (uint32_t*)ws;  ws += (size_t)B * n * sizeof(uint32_t);
    uint32_t* max_i      = (uint32_t*)ws;  ws += (size_t)B * n * sizeof(uint32_t);
    size_t zbytes = (size_t)ws - (size_t)d_ws;
    int*      iou_arg    = (int*)ws;       ws += (size_t)B * L * sizeof(int);
    int*      assigned_g = (int*)ws;       ws += (size_t)B * L * sizeof(int);
    float*    align_val  = (float*)ws;     ws += (size_t)B * L * sizeof(float);

    float*  out_labels = (float*)d_out;
    float4* out_bboxes = (float4*)((float*)d_out + (size_t)B * L);
    float*  out_scores = (float*)d_out + (size_t)B * L * 5;

    hipMemsetAsync(maskbits, 0, zbytes, stream);

    {
        dim3 grid((L + 255) / 256, B);
        k_iou_argmax<<<grid, 256, n * sizeof(float4), stream>>>(
            pred_bboxes, gt_bboxes, iou_arg, B, L, n);
    }
    k_topk<<<B * n, 256, 0, stream>>>(
        pred_scores, pred_bboxes, anchor_points, gt_labels, gt_bboxes,
        pad_gt_mask, maskbits, B, L, C, n, W);
    k_assign<<<(B * L + 255) / 256, 256, 0, stream>>>(
        pred_scores, pred_bboxes, gt_bboxes, gt_labels, maskbits, iou_arg,
        bg_ptr, assigned_g, align_val, max_m, max_i, out_labels, out_bboxes,
        B, L, C, n, W);
    {
        int total = B * L * C;
        k_scores<<<(total + 255) / 256, 256, 0, stream>>>(
            assigned_g, align_val, max_m, max_i, gt_labels, bg_ptr,
            out_scores, B, L, C, n, total);
    }
}

// Round 3
// 80.242 us; speedup vs baseline: 2.6597x; 1.6157x over previous
//
#include <hip/hip_runtime.h>
#include <cstdint>

#define NTOPK 13
#define FEPS 1e-9f
#define CAP 64        // per-(b,g) positive-key capacity (p ~ 3 here)
#define GSPLIT 4      // gt-dimension split of the scan grid

// ---------------------------------------------------------------------------
// metric[l] for one gt. Identical arithmetic to the reference.
// ---------------------------------------------------------------------------
__device__ __forceinline__ float tal_metric(int l, float4 gb, float ag,
                                            const float4* __restrict__ pb,
                                            const float* __restrict__ ps,
                                            const float2* __restrict__ apt,
                                            int C) {
    float2 a = apt[l];
    float dmin = fminf(fminf(a.x - gb.x, a.y - gb.y),
                       fminf(gb.z - a.x, gb.w - a.y));
    float m = 0.0f;
    if (dmin > FEPS) {
        float4 p = pb[l];
        float iw = fmaxf(fminf(gb.z, p.z) - fmaxf(gb.x, p.x), 0.0f);
        float ih = fmaxf(fminf(gb.w, p.w) - fmaxf(gb.y, p.y), 0.0f);
        float inter = iw * ih;
        float ap2 = (p.z - p.x) * (p.w - p.y);
        float iou = inter / (((ag + ap2) - inter) + 1e-9f);
        m = ps[(size_t)l * C] * powf(iou, 6.0f);
    }
    return m;
}

// ---------------------------------------------------------------------------
// Kernel 1: sparse scan. Block = (anchor tile, batch, gt-quarter).
// Thread owns one anchor; loops gts staged in LDS. Positives (metric>0) are
// pushed into per-(b,g) key lists. Also zeroes maskbits (z==0 blocks).
// ---------------------------------------------------------------------------
__global__ __launch_bounds__(256) void k_scan(
        const float* __restrict__ pred_scores,
        const float4* __restrict__ pred_bboxes,
        const float2* __restrict__ anchor_points,
        const int* __restrict__ gt_labels,
        const float4* __restrict__ gt_bboxes,
        const float* __restrict__ pad_gt_mask,
        uint64_t* __restrict__ keys,
        uint32_t* __restrict__ cnt,
        uint32_t* __restrict__ maskbits,
        int B, int L, int C, int n, int W) {
    int b = blockIdx.y;
    int l0 = blockIdx.x * 256;
    int per = (n + GSPLIT - 1) / GSPLIT;
    int gbeg = blockIdx.z * per;
    int gend = min(n, gbeg + per);
    int ng = gend - gbeg;

    extern __shared__ char smem[];
    float4* sbox = (float4*)smem;
    int*    slab = (int*)(sbox + per);

    for (int i = threadIdx.x; i < ng; i += 256) {
        int g = gbeg + i;
        float4 gb = gt_bboxes[(size_t)b * n + g];
        if (pad_gt_mask[(size_t)b * n + g] == 0.0f) {
            gb.x = 1e30f; gb.y = 1e30f; gb.z = -1e30f; gb.w = -1e30f;  // never in-gts
        }
        sbox[i] = gb;
        slab[i] = gt_labels[(size_t)b * n + g];
    }
    if (blockIdx.z == 0) {  // zero maskbits rows for this (b, tile)
        int rows = min(256, L - l0);
        uint32_t* mb = maskbits + ((size_t)b * L + l0) * W;
        for (int w = threadIdx.x; w < rows * W; w += 256) mb[w] = 0;
    }
    __syncthreads();

    int l = l0 + threadIdx.x;
    if (l >= L) return;
    float2 a = anchor_points[l];
    float4 p = pred_bboxes[(size_t)b * L + l];
    float ap = (p.z - p.x) * (p.w - p.y);
    const float* ps = pred_scores + ((size_t)b * L + l) * C;

    for (int i = 0; i < ng; ++i) {
        float4 gb = sbox[i];
        float dmin = fminf(fminf(a.x - gb.x, a.y - gb.y),
                           fminf(gb.z - a.x, gb.w - a.y));
        if (dmin > FEPS) {
            float iw = fmaxf(fminf(gb.z, p.z) - fmaxf(gb.x, p.x), 0.0f);
            float ih = fmaxf(fminf(gb.w, p.w) - fmaxf(gb.y, p.y), 0.0f);
            float inter = iw * ih;
            if (inter > 0.0f) {
                float ag = (gb.z - gb.x) * (gb.w - gb.y);
                float iou = inter / (((ag + ap) - inter) + 1e-9f);
                float m = ps[slab[i]] * powf(iou, 6.0f);
                if (m > 0.0f) {
                    int bg = b * n + gbeg + i;
                    uint32_t off = atomicAdd(&cnt[bg], 1u);
                    if (off < CAP)
                        keys[(size_t)bg * CAP + off] =
                            ((uint64_t)__float_as_uint(m) << 32) | (uint32_t)(~l);
                }
            }
        }
    }
}

// ---------------------------------------------------------------------------
// Kernel 2: selection. One wave per (b,g), fully register/shfl-based:
//  - p<=CAP: load keys, min(p,13) shfl-max rounds (key desc == value desc,
//    index asc), ballot-based zero-fill of lowest-index zero-metric anchors.
//  - p>CAP: dense per-wave recompute fallback (correctness only).
// Picks set bit g in maskbits iff anchor in-gts.
// ---------------------------------------------------------------------------
__global__ __launch_bounds__(256) void k_select(
        const float* __restrict__ pred_scores,
        const float4* __restrict__ pred_bboxes,
        const float2* __restrict__ anchor_points,
        const int* __restrict__ gt_labels,
        const float4* __restrict__ gt_bboxes,
        const float* __restrict__ pad_gt_mask,
        const uint64_t* __restrict__ keys,
        const uint32_t* __restrict__ cnt,
        uint32_t* __restrict__ maskbits,
        int B, int L, int C, int n, int W) {
    int wid = threadIdx.x >> 6;
    int lane = threadIdx.x & 63;
    int bg = blockIdx.x * 4 + wid;
    if (bg >= B * n) return;
    if (pad_gt_mask[bg] == 0.0f) return;
    int b = bg / n;
    int g = bg - b * n;

    uint32_t p = cnt[bg];
    int mypick = -1;

    if (p <= CAP) {
        uint64_t mykey = (lane < (int)p) ? keys[(size_t)bg * CAP + lane] : 0ull;
        int np = min((int)p, NTOPK);
        for (int k = 0; k < np; ++k) {
            uint64_t mk = mykey;
            for (int s = 1; s < 64; s <<= 1) {
                uint64_t o = __shfl_xor((unsigned long long)mk, s);
                if (o > mk) mk = o;
            }
            if (lane == k) mypick = (int)~(uint32_t)mk;
            if (mykey == mk) mykey = 0ull;  // unique owner (index embedded)
        }
        // zero-fill: lowest-index anchors not among the positive picks
        int fill = np, c = 0;
        while (fill < NTOPK) {
            bool inP = __ballot(lane < np && mypick == c) != 0ull;
            if (!inP) {
                if (lane == fill) mypick = c;
                ++fill;
            }
            ++c;
        }
    } else {
        // dense fallback (not taken for this data): 13 recompute rounds
        float4 gb = gt_bboxes[bg];
        float ag = (gb.z - gb.x) * (gb.w - gb.y);
        const float4* pb = pred_bboxes + (size_t)b * L;
        const float*  ps = pred_scores + ((size_t)b * L) * C + gt_labels[bg];
        for (int k = 0; k < NTOPK; ++k) {
            uint64_t bk = 0;
            for (int l = lane; l < L; l += 64) {
                bool taken = false;
                for (int j = 0; j < k; ++j)
                    taken |= (__shfl(mypick, j) == l);
                if (taken) continue;
                float m = tal_metric(l, gb, ag, pb, ps, anchor_points, C);
                uint64_t key = ((uint64_t)__float_as_uint(m) << 32) | (uint32_t)(~l);
                if (key > bk) bk = key;
            }
            for (int s = 1; s < 64; s <<= 1) {
                uint64_t o = __shfl_xor((unsigned long long)bk, s);
                if (o > bk) bk = o;
            }
            if (lane == k) mypick = (int)~(uint32_t)bk;
        }
    }

    if (lane < NTOPK) {
        int l = mypick;
        float4 gb = gt_bboxes[bg];
        float2 a = anchor_points[l];
        float dmin = fminf(fminf(a.x - gb.x, a.y - gb.y),
                           fminf(gb.z - a.x, gb.w - a.y));
        if (dmin > FEPS) {
            atomicOr(&maskbits[((size_t)b * L + l) * W + (g >> 5)],
                     1u << (g & 31));
        }
    }
}

// ---------------------------------------------------------------------------
// Kernel 3: per (b,l): resolve assignment (sum>1 -> inline argmax-IoU over
// all gts, first-max semantics), write labels + bboxes, accumulate per-gt
// max(align), max(iou).
// ---------------------------------------------------------------------------
__global__ __launch_bounds__(256) void k_assign(
        const float* __restrict__ pred_scores,
        const float4* __restrict__ pred_bboxes,
        const float4* __restrict__ gt_bboxes,
        const int* __restrict__ gt_labels,
        const uint32_t* __restrict__ maskbits,
        const int* __restrict__ bg_ptr,
        int* __restrict__ assigned_g,
        float* __restrict__ align_val,
        uint32_t* __restrict__ max_m,
        uint32_t* __restrict__ max_i,
        float* __restrict__ out_labels,
        float4* __restrict__ out_bboxes,
        int B, int L, int C, int n, int W) {
    int idx = blockIdx.x * blockDim.x + threadIdx.x;
    if (idx >= B * L) return;
    int b = idx / L;

    int sum = 0, firstg = -1;
    for (int w = 0; w < W; ++w) {
        uint32_t bits = maskbits[(size_t)idx * W + w];
        if (bits && firstg < 0) firstg = w * 32 + __ffs(bits) - 1;
        sum += __popc(bits);
    }

    float4 p = pred_bboxes[idx];
    float ap = (p.z - p.x) * (p.w - p.y);

    int g;
    if (sum == 0) g = -1;
    else if (sum == 1) g = firstg;
    else {
        // is_max_iou replacement: first-max argmax over ALL gts of raw IoU
        float best = -1.0f; int bi = 0;
        for (int gg = 0; gg < n; ++gg) {
            float4 gb = gt_bboxes[(size_t)b * n + gg];
            float iw = fmaxf(fminf(gb.z, p.z) - fmaxf(gb.x, p.x), 0.0f);
            float ih = fmaxf(fminf(gb.w, p.w) - fmaxf(gb.y, p.y), 0.0f);
            float inter = iw * ih;
            float ag = (gb.z - gb.x) * (gb.w - gb.y);
            float iou = inter / (((ag + ap) - inter) + 1e-9f);
            if (iou > best) { best = iou; bi = gg; }
        }
        g = bi;
    }
    assigned_g[idx] = g;

    float av = 0.0f;
    if (g >= 0) {
        float4 gb = gt_bboxes[(size_t)b * n + g];
        float iw = fmaxf(fminf(gb.z, p.z) - fmaxf(gb.x, p.x), 0.0f);
        float ih = fmaxf(fminf(gb.w, p.w) - fmaxf(gb.y, p.y), 0.0f);
        float inter = iw * ih;
        float ag = (gb.z - gb.x) * (gb.w - gb.y);
        float iou = inter / (((ag + ap) - inter) + 1e-9f);
        int label = gt_labels[(size_t)b * n + g];
        float score = pred_scores[(size_t)idx * C + label];
        av = score * powf(iou, 6.0f);
        atomicMax(&max_m[(size_t)b * n + g], __float_as_uint(av));
        atomicMax(&max_i[(size_t)b * n + g], __float_as_uint(iou));
        out_labels[idx] = (float)label;
        out_bboxes[idx] = gb;
    } else {
        out_labels[idx] = (float)(*bg_ptr);
        out_bboxes[idx] = gt_bboxes[(size_t)b * n];  // agi==0 gather, unmasked
    }
    align_val[idx] = av;
}

// ---------------------------------------------------------------------------
// Kernel 4: scores, float4-vectorized (C % 4 == 0 path).
// ---------------------------------------------------------------------------
__global__ __launch_bounds__(256) void k_scores4(
        const int* __restrict__ assigned_g,
        const float* __restrict__ align_val,
        const uint32_t* __restrict__ max_m,
        const uint32_t* __restrict__ max_i,
        const int* __restrict__ gt_labels,
        const int* __restrict__ bg_ptr,
        float4* __restrict__ out_scores,
        int B, int L, int C, int n, int total4) {
    int idx = blockIdx.x * blockDim.x + threadIdx.x;
    if (idx >= total4) return;
    int C4 = C >> 2;
    int c0 = (idx % C4) * 4;
    int bl = idx / C4;
    int g = assigned_g[bl];
    float4 v = make_float4(0.f, 0.f, 0.f, 0.f);
    if (g >= 0) {
        int b = bl / L;
        int label = gt_labels[(size_t)b * n + g];
        int bgi = *bg_ptr;
        float mm = __uint_as_float(max_m[(size_t)b * n + g]);
        float mi = __uint_as_float(max_i[(size_t)b * n + g]);
        float val = align_val[bl] / (mm + FEPS) * mi;
        int cls0 = (c0     < bgi) ? c0     : c0 + 1;
        int cls1 = (c0 + 1 < bgi) ? c0 + 1 : c0 + 2;
        int cls2 = (c0 + 2 < bgi) ? c0 + 2 : c0 + 3;
        int cls3 = (c0 + 3 < bgi) ? c0 + 3 : c0 + 4;
        if (cls0 == label) v.x = val;
        if (cls1 == label) v.y = val;
        if (cls2 == label) v.z = val;
        if (cls3 == label) v.w = val;
    }
    out_scores[idx] = v;
}

__global__ __launch_bounds__(256) void k_scores1(
        const int* __restrict__ assigned_g,
        const float* __restrict__ align_val,
        const uint32_t* __restrict__ max_m,
        const uint32_t* __restrict__ max_i,
        const int* __restrict__ gt_labels,
        const int* __restrict__ bg_ptr,
        float* __restrict__ out_scores,
        int B, int L, int C, int n, int total) {
    int idx = blockIdx.x * blockDim.x + threadIdx.x;
    if (idx >= total) return;
    int c = idx % C;
    int bl = idx / C;
    int g = assigned_g[bl];
    float v = 0.0f;
    if (g >= 0) {
        int b = bl / L;
        int label = gt_labels[(size_t)b * n + g];
        int bgi = *bg_ptr;
        int cls = (c < bgi) ? c : c + 1;
        if (cls == label) {
            float mm = __uint_as_float(max_m[(size_t)b * n + g]);
            float mi = __uint_as_float(max_i[(size_t)b * n + g]);
            v = align_val[bl] / (mm + FEPS) * mi;
        }
    }
    out_scores[idx] = v;
}

// ---------------------------------------------------------------------------
extern "C" void kernel_launch(void* const* d_in, const int* in_sizes, int n_in,
                              void* d_out, int out_size, void* d_ws, size_t ws_size,
                              hipStream_t stream) {
    const float*  pred_scores   = (const float*)d_in[0];
    const float4* pred_bboxes   = (const float4*)d_in[1];
    const float2* anchor_points = (const float2*)d_in[2];
    const int*    gt_labels     = (const int*)d_in[3];
    const float4* gt_bboxes     = (const float4*)d_in[4];
    const float*  pad_gt_mask   = (const float*)d_in[5];
    const int*    bg_ptr        = (const int*)d_in[6];

    const int L = in_sizes[2] / 2;
    const int B = in_sizes[1] / (L * 4);
    const int C = in_sizes[0] / (B * L);
    const int n = in_sizes[3] / B;
    const int W = (n + 31) / 32;

    // zero-initialized region first (single small memset): cnt, max_m, max_i
    char* ws = (char*)d_ws;
    uint32_t* cnt      = (uint32_t*)ws;  ws += (size_t)B * n * sizeof(uint32_t);
    uint32_t* max_m    = (uint32_t*)ws;  ws += (size_t)B * n * sizeof(uint32_t);
    uint32_t* max_i    = (uint32_t*)ws;  ws += (size_t)B * n * sizeof(uint32_t);
    size_t zbytes = (size_t)((char*)ws - (char*)d_ws);
    uint64_t* keys     = (uint64_t*)ws;  ws += (size_t)B * n * CAP * sizeof(uint64_t);
    uint32_t* maskbits = (uint32_t*)ws;  ws += (size_t)B * L * W * sizeof(uint32_t);
    int*      assigned_g = (int*)ws;     ws += (size_t)B * L * sizeof(int);
    float*    align_val  = (float*)ws;   ws += (size_t)B * L * sizeof(float);

    float*  out_labels = (float*)d_out;
    float4* out_bboxes = (float4*)((float*)d_out + (size_t)B * L);
    float*  out_scores = (float*)d_out + (size_t)B * L * 5;

    hipMemsetAsync(d_ws, 0, zbytes, stream);

    {
        int per = (n + GSPLIT - 1) / GSPLIT;
        dim3 grid((L + 255) / 256, B, GSPLIT);
        size_t smem = (size_t)per * (sizeof(float4) + sizeof(int));
        k_scan<<<grid, 256, smem, stream>>>(
            pred_scores, pred_bboxes, anchor_points, gt_labels, gt_bboxes,
            pad_gt_mask, keys, cnt, maskbits, B, L, C, n, W);
    }
    k_select<<<(B * n + 3) / 4, 256, 0, stream>>>(
        pred_scores, pred_bboxes, anchor_points, gt_labels, gt_bboxes,
        pad_gt_mask, keys, cnt, maskbits, B, L, C, n, W);
    k_assign<<<(B * L + 255) / 256, 256, 0, stream>>>(
        pred_scores, pred_bboxes, gt_bboxes, gt_labels, maskbits,
        bg_ptr, assigned_g, align_val, max_m, max_i, out_labels, out_bboxes,
        B, L, C, n, W);
    if ((C & 3) == 0) {
        int total4 = B * L * (C >> 2);
        k_scores4<<<(total4 + 255) / 256, 256, 0, stream>>>(
            assigned_g, align_val, max_m, max_i, gt_labels, bg_ptr,
            (float4*)out_scores, B, L, C, n, total4);
    } else {
        int total = B * L * C;
        k_scores1<<<(total + 255) / 256, 256, 0, stream>>>(
            assigned_g, align_val, max_m, max_i, gt_labels, bg_ptr,
            out_scores, B, L, C, n, total);
    }
}

// Round 4
// 72.495 us; speedup vs baseline: 2.9440x; 1.1069x over previous
//
#include <hip/hip_runtime.h>
#include <cstdint>

#define NTOPK 13
#define FEPS 1e-9f
#define CAP 64        // per-(b,g) positive-key capacity (p ~ 3 here)
#define GSPLIT 4      // gt-dimension split of the scan grid

// ---------------------------------------------------------------------------
// metric[l] for one gt. Identical arithmetic to the reference.
// ---------------------------------------------------------------------------
__device__ __forceinline__ float tal_metric(int l, float4 gb, float ag,
                                            const float4* __restrict__ pb,
                                            const float* __restrict__ ps,
                                            const float2* __restrict__ apt,
                                            int C) {
    float2 a = apt[l];
    float dmin = fminf(fminf(a.x - gb.x, a.y - gb.y),
                       fminf(gb.z - a.x, gb.w - a.y));
    float m = 0.0f;
    if (dmin > FEPS) {
        float4 p = pb[l];
        float iw = fmaxf(fminf(gb.z, p.z) - fmaxf(gb.x, p.x), 0.0f);
        float ih = fmaxf(fminf(gb.w, p.w) - fmaxf(gb.y, p.y), 0.0f);
        float inter = iw * ih;
        float ap2 = (p.z - p.x) * (p.w - p.y);
        float iou = inter / (((ag + ap2) - inter) + 1e-9f);
        m = ps[(size_t)l * C] * powf(iou, 6.0f);
    }
    return m;
}

// ---------------------------------------------------------------------------
// Kernel 1: sparse scan. Block = (anchor tile, batch, gt-quarter).
// Thread owns one anchor; loops gts staged in LDS. Positives (metric>0) are
// pushed into per-(b,g) key lists. Also zeroes maskbits (z==0 blocks).
// ---------------------------------------------------------------------------
__global__ __launch_bounds__(256) void k_scan(
        const float* __restrict__ pred_scores,
        const float4* __restrict__ pred_bboxes,
        const float2* __restrict__ anchor_points,
        const int* __restrict__ gt_labels,
        const float4* __restrict__ gt_bboxes,
        const float* __restrict__ pad_gt_mask,
        uint64_t* __restrict__ keys,
        uint32_t* __restrict__ cnt,
        uint32_t* __restrict__ maskbits,
        int B, int L, int C, int n, int W) {
    int b = blockIdx.y;
    int l0 = blockIdx.x * 256;
    int per = (n + GSPLIT - 1) / GSPLIT;
    int gbeg = blockIdx.z * per;
    int gend = min(n, gbeg + per);
    int ng = gend - gbeg;

    extern __shared__ char smem[];
    float4* sbox = (float4*)smem;
    int*    slab = (int*)(sbox + per);

    for (int i = threadIdx.x; i < ng; i += 256) {
        int g = gbeg + i;
        float4 gb = gt_bboxes[(size_t)b * n + g];
        if (pad_gt_mask[(size_t)b * n + g] == 0.0f) {
            gb.x = 1e30f; gb.y = 1e30f; gb.z = -1e30f; gb.w = -1e30f;  // never in-gts
        }
        sbox[i] = gb;
        slab[i] = gt_labels[(size_t)b * n + g];
    }
    if (blockIdx.z == 0) {  // zero maskbits rows for this (b, tile)
        int rows = min(256, L - l0);
        uint32_t* mb = maskbits + ((size_t)b * L + l0) * W;
        for (int w = threadIdx.x; w < rows * W; w += 256) mb[w] = 0;
    }
    __syncthreads();

    int l = l0 + threadIdx.x;
    if (l >= L) return;
    float2 a = anchor_points[l];
    float4 p = pred_bboxes[(size_t)b * L + l];
    float ap = (p.z - p.x) * (p.w - p.y);
    const float* ps = pred_scores + ((size_t)b * L + l) * C;

    for (int i = 0; i < ng; ++i) {
        float4 gb = sbox[i];
        float dmin = fminf(fminf(a.x - gb.x, a.y - gb.y),
                           fminf(gb.z - a.x, gb.w - a.y));
        if (dmin > FEPS) {
            float iw = fmaxf(fminf(gb.z, p.z) - fmaxf(gb.x, p.x), 0.0f);
            float ih = fmaxf(fminf(gb.w, p.w) - fmaxf(gb.y, p.y), 0.0f);
            float inter = iw * ih;
            if (inter > 0.0f) {
                float ag = (gb.z - gb.x) * (gb.w - gb.y);
                float iou = inter / (((ag + ap) - inter) + 1e-9f);
                float m = ps[slab[i]] * powf(iou, 6.0f);
                if (m > 0.0f) {
                    int bg = b * n + gbeg + i;
                    uint32_t off = atomicAdd(&cnt[bg], 1u);
                    if (off < CAP)
                        keys[(size_t)bg * CAP + off] =
                            ((uint64_t)__float_as_uint(m) << 32) | (uint32_t)(~l);
                }
            }
        }
    }
}

// ---------------------------------------------------------------------------
// Kernel 2: selection. One wave per (b,g), fully register/shfl-based:
//  - p<=CAP: load keys, min(p,13) shfl-max rounds (key desc == value desc,
//    index asc), ballot-based zero-fill of lowest-index zero-metric anchors.
//  - p>CAP: dense per-wave recompute fallback (correctness only).
// Picks set bit g in maskbits iff anchor in-gts.
// ---------------------------------------------------------------------------
__global__ __launch_bounds__(256) void k_select(
        const float* __restrict__ pred_scores,
        const float4* __restrict__ pred_bboxes,
        const float2* __restrict__ anchor_points,
        const int* __restrict__ gt_labels,
        const float4* __restrict__ gt_bboxes,
        const float* __restrict__ pad_gt_mask,
        const uint64_t* __restrict__ keys,
        const uint32_t* __restrict__ cnt,
        uint32_t* __restrict__ maskbits,
        int B, int L, int C, int n, int W) {
    int wid = threadIdx.x >> 6;
    int lane = threadIdx.x & 63;
    int bg = blockIdx.x * 4 + wid;
    if (bg >= B * n) return;
    if (pad_gt_mask[bg] == 0.0f) return;
    int b = bg / n;
    int g = bg - b * n;

    uint32_t p = cnt[bg];
    int mypick = -1;

    if (p <= CAP) {
        uint64_t mykey = (lane < (int)p) ? keys[(size_t)bg * CAP + lane] : 0ull;
        int np = min((int)p, NTOPK);
        for (int k = 0; k < np; ++k) {
            uint64_t mk = mykey;
            for (int s = 1; s < 64; s <<= 1) {
                uint64_t o = __shfl_xor((unsigned long long)mk, s);
                if (o > mk) mk = o;
            }
            if (lane == k) mypick = (int)~(uint32_t)mk;
            if (mykey == mk) mykey = 0ull;  // unique owner (index embedded)
        }
        // zero-fill: lowest-index anchors not among the positive picks
        int fill = np, c = 0;
        while (fill < NTOPK) {
            bool inP = __ballot(lane < np && mypick == c) != 0ull;
            if (!inP) {
                if (lane == fill) mypick = c;
                ++fill;
            }
            ++c;
        }
    } else {
        // dense fallback (not taken for this data): 13 recompute rounds
        float4 gb = gt_bboxes[bg];
        float ag = (gb.z - gb.x) * (gb.w - gb.y);
        const float4* pb = pred_bboxes + (size_t)b * L;
        const float*  ps = pred_scores + ((size_t)b * L) * C + gt_labels[bg];
        for (int k = 0; k < NTOPK; ++k) {
            uint64_t bk = 0;
            for (int l = lane; l < L; l += 64) {
                bool taken = false;
                for (int j = 0; j < k; ++j)
                    taken |= (__shfl(mypick, j) == l);
                if (taken) continue;
                float m = tal_metric(l, gb, ag, pb, ps, anchor_points, C);
                uint64_t key = ((uint64_t)__float_as_uint(m) << 32) | (uint32_t)(~l);
                if (key > bk) bk = key;
            }
            for (int s = 1; s < 64; s <<= 1) {
                uint64_t o = __shfl_xor((unsigned long long)bk, s);
                if (o > bk) bk = o;
            }
            if (lane == k) mypick = (int)~(uint32_t)bk;
        }
    }

    if (lane < NTOPK) {
        int l = mypick;
        float4 gb = gt_bboxes[bg];
        float2 a = anchor_points[l];
        float dmin = fminf(fminf(a.x - gb.x, a.y - gb.y),
                           fminf(gb.z - a.x, gb.w - a.y));
        if (dmin > FEPS) {
            atomicOr(&maskbits[((size_t)b * L + l) * W + (g >> 5)],
                     1u << (g & 31));
        }
    }
}

// ---------------------------------------------------------------------------
// Kernel 3: per (b,l): resolve assignment. Grid (L-tiles, B); all n gt boxes
// + labels staged in LDS so the sum>1 argmax-IoU loop and the assigned-gt
// gathers never touch global memory.
// ---------------------------------------------------------------------------
__global__ __launch_bounds__(256) void k_assign(
        const float* __restrict__ pred_scores,
        const float4* __restrict__ pred_bboxes,
        const float4* __restrict__ gt_bboxes,
        const int* __restrict__ gt_labels,
        const uint32_t* __restrict__ maskbits,
        const int* __restrict__ bg_ptr,
        int* __restrict__ assigned_g,
        float* __restrict__ align_val,
        uint32_t* __restrict__ max_m,
        uint32_t* __restrict__ max_i,
        float* __restrict__ out_labels,
        float4* __restrict__ out_bboxes,
        int B, int L, int C, int n, int W) {
    extern __shared__ char smem[];
    float4* sbox = (float4*)smem;       // raw gt boxes (reference uses unmasked)
    int*    slab = (int*)(sbox + n);
    int b = blockIdx.y;
    for (int i = threadIdx.x; i < n; i += 256) {
        sbox[i] = gt_bboxes[(size_t)b * n + i];
        slab[i] = gt_labels[(size_t)b * n + i];
    }
    __syncthreads();

    int l = blockIdx.x * 256 + threadIdx.x;
    if (l >= L) return;
    size_t idx = (size_t)b * L + l;

    int sum = 0, firstg = -1;
    for (int w = 0; w < W; ++w) {
        uint32_t bits = maskbits[idx * W + w];
        if (bits && firstg < 0) firstg = w * 32 + __ffs(bits) - 1;
        sum += __popc(bits);
    }

    float4 p = pred_bboxes[idx];
    float ap = (p.z - p.x) * (p.w - p.y);

    int g;
    if (sum == 0) g = -1;
    else if (sum == 1) g = firstg;
    else {
        // is_max_iou: first-max argmax over ALL gts of raw IoU (LDS reads)
        float best = -1.0f; int bi = 0;
        for (int gg = 0; gg < n; ++gg) {
            float4 gb = sbox[gg];
            float iw = fmaxf(fminf(gb.z, p.z) - fmaxf(gb.x, p.x), 0.0f);
            float ih = fmaxf(fminf(gb.w, p.w) - fmaxf(gb.y, p.y), 0.0f);
            float inter = iw * ih;
            float ag = (gb.z - gb.x) * (gb.w - gb.y);
            float iou = inter / (((ag + ap) - inter) + 1e-9f);
            if (iou > best) { best = iou; bi = gg; }
        }
        g = bi;
    }
    assigned_g[idx] = g;

    float av = 0.0f;
    if (g >= 0) {
        float4 gb = sbox[g];
        float iw = fmaxf(fminf(gb.z, p.z) - fmaxf(gb.x, p.x), 0.0f);
        float ih = fmaxf(fminf(gb.w, p.w) - fmaxf(gb.y, p.y), 0.0f);
        float inter = iw * ih;
        float ag = (gb.z - gb.x) * (gb.w - gb.y);
        float iou = inter / (((ag + ap) - inter) + 1e-9f);
        int label = slab[g];
        float score = pred_scores[idx * C + label];
        av = score * powf(iou, 6.0f);
        atomicMax(&max_m[(size_t)b * n + g], __float_as_uint(av));
        atomicMax(&max_i[(size_t)b * n + g], __float_as_uint(iou));
        out_labels[idx] = (float)label;
        out_bboxes[idx] = gb;
    } else {
        out_labels[idx] = (float)(*bg_ptr);
        out_bboxes[idx] = sbox[0];  // agi==0 gather, unmasked
    }
    align_val[idx] = av;
}

// ---------------------------------------------------------------------------
// Kernel 4: scores, float4-vectorized (C % 4 == 0 path).
// ---------------------------------------------------------------------------
__global__ __launch_bounds__(256) void k_scores4(
        const int* __restrict__ assigned_g,
        const float* __restrict__ align_val,
        const uint32_t* __restrict__ max_m,
        const uint32_t* __restrict__ max_i,
        const int* __restrict__ gt_labels,
        const int* __restrict__ bg_ptr,
        float4* __restrict__ out_scores,
        int B, int L, int C, int n, int total4) {
    int idx = blockIdx.x * blockDim.x + threadIdx.x;
    if (idx >= total4) return;
    int C4 = C >> 2;
    int c0 = (idx % C4) * 4;
    int bl = idx / C4;
    int g = assigned_g[bl];
    float4 v = make_float4(0.f, 0.f, 0.f, 0.f);
    if (g >= 0) {
        int b = bl / L;
        int label = gt_labels[(size_t)b * n + g];
        int bgi = *bg_ptr;
        float mm = __uint_as_float(max_m[(size_t)b * n + g]);
        float mi = __uint_as_float(max_i[(size_t)b * n + g]);
        float val = align_val[bl] / (mm + FEPS) * mi;
        int cls0 = (c0     < bgi) ? c0     : c0 + 1;
        int cls1 = (c0 + 1 < bgi) ? c0 + 1 : c0 + 2;
        int cls2 = (c0 + 2 < bgi) ? c0 + 2 : c0 + 3;
        int cls3 = (c0 + 3 < bgi) ? c0 + 3 : c0 + 4;
        if (cls0 == label) v.x = val;
        if (cls1 == label) v.y = val;
        if (cls2 == label) v.z = val;
        if (cls3 == label) v.w = val;
    }
    out_scores[idx] = v;
}

__global__ __launch_bounds__(256) void k_scores1(
        const int* __restrict__ assigned_g,
        const float* __restrict__ align_val,
        const uint32_t* __restrict__ max_m,
        const uint32_t* __restrict__ max_i,
        const int* __restrict__ gt_labels,
        const int* __restrict__ bg_ptr,
        float* __restrict__ out_scores,
        int B, int L, int C, int n, int total) {
    int idx = blockIdx.x * blockDim.x + threadIdx.x;
    if (idx >= total) return;
    int c = idx % C;
    int bl = idx / C;
    int g = assigned_g[bl];
    float v = 0.0f;
    if (g >= 0) {
        int b = bl / L;
        int label = gt_labels[(size_t)b * n + g];
        int bgi = *bg_ptr;
        int cls = (c < bgi) ? c : c + 1;
        if (cls == label) {
            float mm = __uint_as_float(max_m[(size_t)b * n + g]);
            float mi = __uint_as_float(max_i[(size_t)b * n + g]);
            v = align_val[bl] / (mm + FEPS) * mi;
        }
    }
    out_scores[idx] = v;
}

// ---------------------------------------------------------------------------
extern "C" void kernel_launch(void* const* d_in, const int* in_sizes, int n_in,
                              void* d_out, int out_size, void* d_ws, size_t ws_size,
                              hipStream_t stream) {
    const float*  pred_scores   = (const float*)d_in[0];
    const float4* pred_bboxes   = (const float4*)d_in[1];
    const float2* anchor_points = (const float2*)d_in[2];
    const int*    gt_labels     = (const int*)d_in[3];
    const float4* gt_bboxes     = (const float4*)d_in[4];
    const float*  pad_gt_mask   = (const float*)d_in[5];
    const int*    bg_ptr        = (const int*)d_in[6];

    const int L = in_sizes[2] / 2;
    const int B = in_sizes[1] / (L * 4);
    const int C = in_sizes[0] / (B * L);
    const int n = in_sizes[3] / B;
    const int W = (n + 31) / 32;

    // zero-initialized region first (single small memset): cnt, max_m, max_i
    char* ws = (char*)d_ws;
    uint32_t* cnt      = (uint32_t*)ws;  ws += (size_t)B * n * sizeof(uint32_t);
    uint32_t* max_m    = (uint32_t*)ws;  ws += (size_t)B * n * sizeof(uint32_t);
    uint32_t* max_i    = (uint32_t*)ws;  ws += (size_t)B * n * sizeof(uint32_t);
    size_t zbytes = (size_t)((char*)ws - (char*)d_ws);
    uint64_t* keys     = (uint64_t*)ws;  ws += (size_t)B * n * CAP * sizeof(uint64_t);
    uint32_t* maskbits = (uint32_t*)ws;  ws += (size_t)B * L * W * sizeof(uint32_t);
    int*      assigned_g = (int*)ws;     ws += (size_t)B * L * sizeof(int);
    float*    align_val  = (float*)ws;   ws += (size_t)B * L * sizeof(float);

    float*  out_labels = (float*)d_out;
    float4* out_bboxes = (float4*)((float*)d_out + (size_t)B * L);
    float*  out_scores = (float*)d_out + (size_t)B * L * 5;

    hipMemsetAsync(d_ws, 0, zbytes, stream);

    {
        int per = (n + GSPLIT - 1) / GSPLIT;
        dim3 grid((L + 255) / 256, B, GSPLIT);
        size_t smem = (size_t)per * (sizeof(float4) + sizeof(int));
        k_scan<<<grid, 256, smem, stream>>>(
            pred_scores, pred_bboxes, anchor_points, gt_labels, gt_bboxes,
            pad_gt_mask, keys, cnt, maskbits, B, L, C, n, W);
    }
    k_select<<<(B * n + 3) / 4, 256, 0, stream>>>(
        pred_scores, pred_bboxes, anchor_points, gt_labels, gt_bboxes,
        pad_gt_mask, keys, cnt, maskbits, B, L, C, n, W);
    {
        dim3 grid((L + 255) / 256, B);
        size_t smem = (size_t)n * (sizeof(float4) + sizeof(int));
        k_assign<<<grid, 256, smem, stream>>>(
            pred_scores, pred_bboxes, gt_bboxes, gt_labels, maskbits,
            bg_ptr, assigned_g, align_val, max_m, max_i, out_labels, out_bboxes,
            B, L, C, n, W);
    }
    if ((C & 3) == 0) {
        int total4 = B * L * (C >> 2);
        k_scores4<<<(total4 + 255) / 256, 256, 0, stream>>>(
            assigned_g, align_val, max_m, max_i, gt_labels, bg_ptr,
            (float4*)out_scores, B, L, C, n, total4);
    } else {
        int total = B * L * C;
        k_scores1<<<(total + 255) / 256, 256, 0, stream>>>(
            assigned_g, align_val, max_m, max_i, gt_labels, bg_ptr,
            out_scores, B, L, C, n, total);
    }
}